// Round 3
// baseline (19861.853 us; speedup 1.0000x reference)
//
#include <hip/hip_runtime.h>

#define T_STEPS 4096
#define M_BATCH 512
#define D_INP   11
#define N_HID   51
#define G4      204    // 4*N gates
#define BT      16     // batch tile per block
#define NTILE   13     // ceil(204/16) gate tiles
#define THREADS 512    // 8 waves

typedef __bf16 bf16x8 __attribute__((ext_vector_type(8)));
typedef float  f32x4  __attribute__((ext_vector_type(4)));

union BF8 { bf16x8 v; unsigned short u[8]; };

__device__ inline unsigned short f2bf(float f) {           // fp32 -> bf16 RNE
    unsigned u = __builtin_bit_cast(unsigned, f);
    return (unsigned short)((u + 0x7FFFu + ((u >> 16) & 1u)) >> 16);
}
__device__ inline float bf2f(unsigned short h) {
    unsigned u = ((unsigned)h) << 16;
    return __builtin_bit_cast(float, u);
}
// act = sigmoid(v) (isg=false) or tanh(v) (isg=true), branch-free saturating
__device__ inline float sigm(float v) {
    float e = __expf(-v);
    return __builtin_amdgcn_rcpf(1.0f + e);
}
__device__ inline float tanhf_fast(float v) {
    float e = __expf(-2.0f * v);
    return 2.0f * __builtin_amdgcn_rcpf(1.0f + e) - 1.0f;
}

#define MFMA(a, b, c) __builtin_amdgcn_mfma_f32_16x16x32_bf16((a), (b), (c), 0, 0, 0)

__global__ __launch_bounds__(THREADS, 2)
void lstm2_mfma(
    const float* __restrict__ input,   // [T, M, 11]
    const float* __restrict__ W_ih1,   // [204, 11]
    const float* __restrict__ W_hh1,   // [204, 51]
    const float* __restrict__ b_ih1,
    const float* __restrict__ b_hh1,
    const float* __restrict__ W_ih2,   // [204, 51]
    const float* __restrict__ W_hh2,   // [204, 51]
    const float* __restrict__ b_ih2,
    const float* __restrict__ b_hh2,
    const float* __restrict__ W_lin,   // [1, 51]
    const float* __restrict__ b_lin,
    float* __restrict__ out)           // [M, T]
{
    const int tid  = threadIdx.x;
    const int wave = tid >> 6;         // 0..7
    const int lane = tid & 63;
    const int quad = lane >> 4;        // 0..3
    const int ncol = lane & 15;        // batch col for MFMA A(m)/B(n)/D(n)
    const int b_u  = tid >> 5;         // 0..15  (update-phase batch)
    const int g_u  = tid & 31;         // 0..31  (update-phase unit group)
    const int base = blockIdx.x * BT;

    // ---- LDS ----
    // B1: layer-1 RHS [x(11); h1(51)] packed bf16 hi/lo: [ks(2)][part(2)][quad(4)][n(16)][j(8)]
    // B2: layer-2 RHS [h1 @k0..50 ; h2 @k64..114]:        [ks(4)][part(2)][quad(4)][n(16)][j(8)]
    __shared__ unsigned short sB1[2 * 2 * 4 * 16 * 8];   // 4 KB
    __shared__ unsigned short sB2[4 * 2 * 4 * 16 * 8];   // 8 KB
    __shared__ float sAct1[208 * 17];                    // stride 17: conflict-light
    __shared__ float sAct2[208 * 17];

    // zero B-operand LDS (covers zero-init h-state and all k-padding)
    {
        unsigned* z1 = (unsigned*)sB1;
        unsigned* z2 = (unsigned*)sB2;
        for (int i = tid; i < 1024; i += THREADS) z1[i] = 0u;
        for (int i = tid; i < 2048; i += THREADS) z2[i] = 0u;
    }

    // ---- persistent weight fragments (bf16 hi/lo split) ----
    // wave w owns gate-tile w, and tile 8+w if w<5  (13 tiles total)
    bf16x8 w1h[2][2], w1l[2][2];       // [slot][kstep]
    bf16x8 w2h[2][4], w2l[2][4];
    float  bias1v[2][4], bias2v[2][4];
    float  Sav[2][4], Aav[2][4], Bav[2][4];
    const int nslot = (wave < 5) ? 2 : 1;

    for (int s = 0; s < 2; ++s) {
        if (s >= nslot) break;
        const int tau = (s == 0) ? wave : 8 + wave;
        const int m   = tau * 16 + ncol;            // A-operand row = lane&15
        #pragma unroll
        for (int ks = 0; ks < 2; ++ks) {            // layer 1, K=64 (x:0..10, h1:11..61)
            BF8 hi, lo;
            #pragma unroll
            for (int j = 0; j < 8; ++j) {
                int k = ks * 32 + quad * 8 + j;
                float w = 0.0f;
                if (m < G4) {
                    if (k < D_INP)               w = W_ih1[m * D_INP + k];
                    else if (k < D_INP + N_HID)  w = W_hh1[m * N_HID + (k - D_INP)];
                }
                unsigned short hs = f2bf(w);
                hi.u[j] = hs;
                lo.u[j] = f2bf(w - bf2f(hs));
            }
            w1h[s][ks] = hi.v; w1l[s][ks] = lo.v;
        }
        #pragma unroll
        for (int ks = 0; ks < 4; ++ks) {            // layer 2, K=128 (h1:0..50, h2:64..114)
            BF8 hi, lo;
            #pragma unroll
            for (int j = 0; j < 8; ++j) {
                int k = ks * 32 + quad * 8 + j;
                float w = 0.0f;
                if (m < G4) {
                    if (k < N_HID)                      w = W_ih2[m * N_HID + k];
                    else if (k >= 64 && k < 64 + N_HID) w = W_hh2[m * N_HID + (k - 64)];
                }
                unsigned short hs = f2bf(w);
                hi.u[j] = hs;
                lo.u[j] = f2bf(w - bf2f(hs));
            }
            w2h[s][ks] = hi.v; w2l[s][ks] = lo.v;
        }
        #pragma unroll
        for (int r = 0; r < 4; ++r) {               // D-row = quad*4 + r
            int mm = tau * 16 + quad * 4 + r;
            bool ok  = (mm < G4);
            bias1v[s][r] = ok ? (b_ih1[mm] + b_hh1[mm]) : 0.0f;
            bias2v[s][r] = ok ? (b_ih2[mm] + b_hh2[mm]) : 0.0f;
            bool isg = (mm >= 2 * N_HID) && (mm < 3 * N_HID);
            Sav[s][r] = isg ? 2.0f : 1.0f;
            Aav[s][r] = isg ? 2.0f : 1.0f;
            Bav[s][r] = isg ? -1.0f : 0.0f;
        }
    }

    // update-phase constants
    const int   n0 = g_u;                      // unit 0 (always < 51)
    const int   n1 = g_u + 32;                 // unit 1 (valid if < 51)
    const bool  has1 = (n1 < N_HID);
    const float wlin0 = W_lin[n0];
    const float wlin1 = has1 ? W_lin[n1] : 0.0f;
    const float blin  = b_lin[0];
    float c1_0 = 0.0f, c1_1 = 0.0f, c2_0 = 0.0f, c2_1 = 0.0f;

    // x pipeline: write x(0) now; xr1 = x(1), xr2 = x(2) in flight
    float xr1 = 0.0f, xr2 = 0.0f;
    if (g_u < D_INP) {
        const size_t stride = (size_t)M_BATCH * D_INP;
        const float* xp = input + (size_t)(base + b_u) * D_INP + g_u;
        float x0 = xp[0];
        int k = g_u, q = k >> 3, j = k & 7;
        unsigned short hs = f2bf(x0);
        sB1[((0 * 2 + 0) * 4 + q) * 128 + b_u * 8 + j] = hs;
        sB1[((0 * 2 + 1) * 4 + q) * 128 + b_u * 8 + j] = f2bf(x0 - bf2f(hs));
        xr1 = xp[stride];
        xr2 = xp[2 * stride];
    }
    __syncthreads();

    const bf16x8* pB1 = (const bf16x8*)sB1;
    const bf16x8* pB2 = (const bf16x8*)sB2;

    for (int t = 0; t < T_STEPS; ++t) {
        // issue x(t+3) load early (2-step prefetch distance)
        float xnew = 0.0f;
        if (g_u < D_INP) {
            int t3 = t + 3; if (t3 > T_STEPS - 1) t3 = T_STEPS - 1;
            xnew = input[((size_t)t3 * M_BATCH + base + b_u) * D_INP + g_u];
        }

        // ================= gates1: D = W1cat x [x;h1] =================
        {
            bf16x8 bh0 = pB1[((0 * 2 + 0) * 4 + quad) * 16 + ncol];
            bf16x8 bl0 = pB1[((0 * 2 + 1) * 4 + quad) * 16 + ncol];
            bf16x8 bh1 = pB1[((1 * 2 + 0) * 4 + quad) * 16 + ncol];
            bf16x8 bl1 = pB1[((1 * 2 + 1) * 4 + quad) * 16 + ncol];
            #pragma unroll
            for (int s = 0; s < 2; ++s) {
                if (s >= nslot) break;
                const int tau = (s == 0) ? wave : 8 + wave;
                f32x4 a0 = {0.f, 0.f, 0.f, 0.f}, a1 = {0.f, 0.f, 0.f, 0.f};
                a0 = MFMA(w1h[s][0], bh0, a0);
                a1 = MFMA(w1h[s][1], bh1, a1);
                a0 = MFMA(w1h[s][0], bl0, a0);
                a1 = MFMA(w1h[s][1], bl1, a1);
                a0 = MFMA(w1l[s][0], bh0, a0);
                a1 = MFMA(w1l[s][1], bh1, a1);
                f32x4 d = a0 + a1;
                #pragma unroll
                for (int r = 0; r < 4; ++r) {
                    float v = d[r] + bias1v[s][r];
                    float e = __expf(-Sav[s][r] * v);
                    float a = Aav[s][r] * __builtin_amdgcn_rcpf(1.0f + e) + Bav[s][r];
                    sAct1[(tau * 16 + quad * 4 + r) * 17 + ncol] = a;
                }
            }
        }
        __syncthreads();                               // B1

        // ================= update1: c1,h1 (thread = (b_u, g_u)) =================
        {
            // unit n0
            {
                float iv = sAct1[(0 * N_HID + n0) * 17 + b_u];
                float fv = sAct1[(1 * N_HID + n0) * 17 + b_u];
                float gv = sAct1[(2 * N_HID + n0) * 17 + b_u];
                float ov = sAct1[(3 * N_HID + n0) * 17 + b_u];
                c1_0 = fv * c1_0 + iv * gv;
                float h = ov * tanhf_fast(c1_0);
                unsigned short hs = f2bf(h);
                unsigned short ls = f2bf(h - bf2f(hs));
                int k = D_INP + n0, ks = k >> 5, w = k & 31, q = w >> 3, j = w & 7;
                sB1[((ks * 2 + 0) * 4 + q) * 128 + b_u * 8 + j] = hs;
                sB1[((ks * 2 + 1) * 4 + q) * 128 + b_u * 8 + j] = ls;
                int k2 = n0, ks2 = k2 >> 5, w2 = k2 & 31, q2 = w2 >> 3, j2 = w2 & 7;
                sB2[((ks2 * 2 + 0) * 4 + q2) * 128 + b_u * 8 + j2] = hs;
                sB2[((ks2 * 2 + 1) * 4 + q2) * 128 + b_u * 8 + j2] = ls;
            }
            if (has1) {                                // unit n1
                float iv = sAct1[(0 * N_HID + n1) * 17 + b_u];
                float fv = sAct1[(1 * N_HID + n1) * 17 + b_u];
                float gv = sAct1[(2 * N_HID + n1) * 17 + b_u];
                float ov = sAct1[(3 * N_HID + n1) * 17 + b_u];
                c1_1 = fv * c1_1 + iv * gv;
                float h = ov * tanhf_fast(c1_1);
                unsigned short hs = f2bf(h);
                unsigned short ls = f2bf(h - bf2f(hs));
                int k = D_INP + n1, ks = k >> 5, w = k & 31, q = w >> 3, j = w & 7;
                sB1[((ks * 2 + 0) * 4 + q) * 128 + b_u * 8 + j] = hs;
                sB1[((ks * 2 + 1) * 4 + q) * 128 + b_u * 8 + j] = ls;
                int k2 = n1, ks2 = k2 >> 5, w2 = k2 & 31, q2 = w2 >> 3, j2 = w2 & 7;
                sB2[((ks2 * 2 + 0) * 4 + q2) * 128 + b_u * 8 + j2] = hs;
                sB2[((ks2 * 2 + 1) * 4 + q2) * 128 + b_u * 8 + j2] = ls;
            }
            // stash x(t+1) into B1 x-region (k = g_u < 11 => ks 0)
            if (g_u < D_INP) {
                int q = g_u >> 3, j = g_u & 7;
                unsigned short hs = f2bf(xr1);
                sB1[((0 * 2 + 0) * 4 + q) * 128 + b_u * 8 + j] = hs;
                sB1[((0 * 2 + 1) * 4 + q) * 128 + b_u * 8 + j] = f2bf(xr1 - bf2f(hs));
            }
        }
        __syncthreads();                               // B2

        // ================= gates2: D = W2cat x [h1;h2] =================
        {
            bf16x8 bh[4], bl[4];
            #pragma unroll
            for (int ks = 0; ks < 4; ++ks) {
                bh[ks] = pB2[((ks * 2 + 0) * 4 + quad) * 16 + ncol];
                bl[ks] = pB2[((ks * 2 + 1) * 4 + quad) * 16 + ncol];
            }
            #pragma unroll
            for (int s = 0; s < 2; ++s) {
                if (s >= nslot) break;
                const int tau = (s == 0) ? wave : 8 + wave;
                f32x4 a0 = {0.f, 0.f, 0.f, 0.f}, a1 = {0.f, 0.f, 0.f, 0.f};
                #pragma unroll
                for (int ks = 0; ks < 4; ++ks) {
                    f32x4& acc = (ks < 2) ? a0 : a1;
                    acc = MFMA(w2h[s][ks], bh[ks], acc);
                    acc = MFMA(w2h[s][ks], bl[ks], acc);
                    acc = MFMA(w2l[s][ks], bh[ks], acc);
                }
                f32x4 d = a0 + a1;
                #pragma unroll
                for (int r = 0; r < 4; ++r) {
                    float v = d[r] + bias2v[s][r];
                    float e = __expf(-Sav[s][r] * v);
                    float a = Aav[s][r] * __builtin_amdgcn_rcpf(1.0f + e) + Bav[s][r];
                    sAct2[(tau * 16 + quad * 4 + r) * 17 + ncol] = a;
                }
            }
        }
        __syncthreads();                               // B3

        // ================= update2: c2,h2 + projection =================
        {
            float part = 0.0f;
            {
                float iv = sAct2[(0 * N_HID + n0) * 17 + b_u];
                float fv = sAct2[(1 * N_HID + n0) * 17 + b_u];
                float gv = sAct2[(2 * N_HID + n0) * 17 + b_u];
                float ov = sAct2[(3 * N_HID + n0) * 17 + b_u];
                c2_0 = fv * c2_0 + iv * gv;
                float h = ov * tanhf_fast(c2_0);
                unsigned short hs = f2bf(h);
                unsigned short ls = f2bf(h - bf2f(hs));
                int k = 64 + n0, ks = k >> 5, w = k & 31, q = w >> 3, j = w & 7;
                sB2[((ks * 2 + 0) * 4 + q) * 128 + b_u * 8 + j] = hs;
                sB2[((ks * 2 + 1) * 4 + q) * 128 + b_u * 8 + j] = ls;
                part = wlin0 * h;
            }
            if (has1) {
                float iv = sAct2[(0 * N_HID + n1) * 17 + b_u];
                float fv = sAct2[(1 * N_HID + n1) * 17 + b_u];
                float gv = sAct2[(2 * N_HID + n1) * 17 + b_u];
                float ov = sAct2[(3 * N_HID + n1) * 17 + b_u];
                c2_1 = fv * c2_1 + iv * gv;
                float h = ov * tanhf_fast(c2_1);
                unsigned short hs = f2bf(h);
                unsigned short ls = f2bf(h - bf2f(hs));
                int k = 64 + n1, ks = k >> 5, w = k & 31, q = w >> 3, j = w & 7;
                sB2[((ks * 2 + 0) * 4 + q) * 128 + b_u * 8 + j] = hs;
                sB2[((ks * 2 + 1) * 4 + q) * 128 + b_u * 8 + j] = ls;
                part += wlin1 * h;
            }
            // reduce over g_u (32 consecutive lanes, same half-wave)
            #pragma unroll
            for (int off = 1; off < 32; off <<= 1)
                part += __shfl_xor(part, off, 64);
            if (g_u == 0) out[(size_t)(base + b_u) * T_STEPS + t] = part + blin;
        }

        // rotate x pipeline
        xr1 = xr2;
        xr2 = xnew;
    }
}

extern "C" void kernel_launch(void* const* d_in, const int* in_sizes, int n_in,
                              void* d_out, int out_size, void* d_ws, size_t ws_size,
                              hipStream_t stream) {
    const float* input = (const float*)d_in[0];
    const float* W_ih1 = (const float*)d_in[1];
    const float* W_hh1 = (const float*)d_in[2];
    const float* b_ih1 = (const float*)d_in[3];
    const float* b_hh1 = (const float*)d_in[4];
    const float* W_ih2 = (const float*)d_in[5];
    const float* W_hh2 = (const float*)d_in[6];
    const float* b_ih2 = (const float*)d_in[7];
    const float* b_hh2 = (const float*)d_in[8];
    const float* W_lin = (const float*)d_in[9];
    const float* b_lin = (const float*)d_in[10];
    float* out = (float*)d_out;

    lstm2_mfma<<<M_BATCH / BT, THREADS, 0, stream>>>(
        input, W_ih1, W_hh1, b_ih1, b_hh1,
        W_ih2, W_hh2, b_ih2, b_hh2, W_lin, b_lin, out);
}

// Round 4
// 19523.030 us; speedup vs baseline: 1.0174x; 1.0174x over previous
//
#include <hip/hip_runtime.h>

#define T_STEPS 4096
#define M_BATCH 512
#define D_INP   11
#define N_HID   51
#define BT      16     // batch tile per block (MFMA N dim)
#define THREADS 256    // 4 waves

typedef __bf16 bf16x8 __attribute__((ext_vector_type(8)));
typedef float  f32x4  __attribute__((ext_vector_type(4)));

union BF8 { bf16x8 v; unsigned short u[8]; };

__device__ inline unsigned short f2bf(float f) {           // fp32 -> bf16 RNE
    unsigned u = __builtin_bit_cast(unsigned, f);
    return (unsigned short)((u + 0x7FFFu + ((u >> 16) & 1u)) >> 16);
}
__device__ inline float bf2f(unsigned short h) {
    unsigned u = ((unsigned)h) << 16;
    return __builtin_bit_cast(float, u);
}
__device__ inline float sigm(float v) {
    return __builtin_amdgcn_rcpf(1.0f + __expf(-v));
}
__device__ inline float tanh_fast(float v) {
    return 2.0f * __builtin_amdgcn_rcpf(1.0f + __expf(-2.0f * v)) - 1.0f;
}

#define MFMA(a,b,c) __builtin_amdgcn_mfma_f32_16x16x32_bf16((a),(b),(c),0,0,0)

// B-operand LDS layout (per hi/lo array):
//   short_index(k, n) = (k>>5)*544 + ((k&31)>>3)*136 + n*8 + (k&7)
// quad_k stride 136 (=128+8 pad) keeps b64 h-writes ~conflict-free and every
// bf16x8 fragment start 16B-aligned (136 shorts = 272 B = 17*16).
__device__ inline int bidx(int k, int n) {
    return (k >> 5) * 544 + ((k & 31) >> 3) * 136 + n * 8 + (k & 7);
}

__global__ __launch_bounds__(THREADS, 1)
void lstm2_mfma4(const float* __restrict__ input,
                 const float* __restrict__ W_ih1, const float* __restrict__ W_hh1,
                 const float* __restrict__ b_ih1, const float* __restrict__ b_hh1,
                 const float* __restrict__ W_ih2, const float* __restrict__ W_hh2,
                 const float* __restrict__ b_ih2, const float* __restrict__ b_hh2,
                 const float* __restrict__ W_lin, const float* __restrict__ b_lin,
                 float* __restrict__ out)
{
    const int tid  = threadIdx.x;
    const int w    = tid >> 6;       // wave 0..3: owns i,f,g,o tiles of units 16w..16w+15
    const int lane = tid & 63;
    const int quad = lane >> 4;
    const int ncol = lane & 15;      // batch column
    const int base = blockIdx.x * BT;

    // ---- LDS: B operands only. B1 = [x(k0..10); bias1(k11); h1(k12..62)], K=64 (2 ks)
    //           B2 = [h1(k0..50); bias1.0(k63); h2(k64..114)],           K=128 (4 ks)
    __shared__ __align__(16) unsigned short sAll[6528];   // 13 KB
    unsigned short* sB1h = sAll;            // 1088 shorts
    unsigned short* sB1l = sAll + 1088;
    unsigned short* sB2h = sAll + 2176;     // 2176 shorts
    unsigned short* sB2l = sAll + 4352;

    { unsigned* z = (unsigned*)sAll;
      for (int i = tid; i < 3264; i += THREADS) z[i] = 0u; }
    __syncthreads();
    if (tid < BT) {                         // constant-1.0 bias columns (bf16 1.0 = 0x3F80)
        sB1h[bidx(11, tid)] = 0x3F80;
        sB2h[bidx(63, tid)] = 0x3F80;
    }

    // ---- persistent A fragments (bf16 hi/lo). Padded row m = s*64 + w*16 + ncol.
    // Real gate row mrow = s*51 + uA (uA = w*16+ncol < 51). Bias folded at k=11 (L1) / k=63 (L2).
    // Hijack: padded row 255 (w==3,s==3,ncol==15) of L2 = W_lin over the h2 k-range.
    bf16x8 a1h[4][2], a1l[4][2], a2h[4][4], a2l[4][4];
    const int  uA    = w * 16 + ncol;
    const bool realA = uA < N_HID;
    for (int s = 0; s < 4; ++s) {
        const int mrow = s * N_HID + uA;
        for (int ks = 0; ks < 2; ++ks) {
            BF8 hi, lo;
            for (int j = 0; j < 8; ++j) {
                int k = ks * 32 + quad * 8 + j;
                float wv = 0.0f;
                if (realA) {
                    if (k < D_INP)                       wv = W_ih1[mrow * D_INP + k];
                    else if (k == 11)                    wv = b_ih1[mrow] + b_hh1[mrow];
                    else if (k >= 12 && k < 12 + N_HID)  wv = W_hh1[mrow * N_HID + (k - 12)];
                }
                hi.u[j] = f2bf(wv); lo.u[j] = f2bf(wv - bf2f(hi.u[j]));
            }
            a1h[s][ks] = hi.v; a1l[s][ks] = lo.v;
        }
        for (int ks = 0; ks < 4; ++ks) {
            BF8 hi, lo;
            for (int j = 0; j < 8; ++j) {
                int k = ks * 32 + quad * 8 + j;
                float wv = 0.0f;
                if (realA) {
                    if (k < N_HID)                       wv = W_ih2[mrow * N_HID + k];
                    else if (k == 63)                    wv = b_ih2[mrow] + b_hh2[mrow];
                    else if (k >= 64 && k < 64 + N_HID)  wv = W_hh2[mrow * N_HID + (k - 64)];
                }
                if (w == 3 && s == 3 && ncol == 15)      // projection row (bias blin added at store)
                    wv = (k >= 64 && k < 64 + N_HID) ? W_lin[k - 64] : 0.0f;
                hi.u[j] = f2bf(wv); lo.u[j] = f2bf(wv - bf2f(hi.u[j]));
            }
            a2h[s][ks] = hi.v; a2l[s][ks] = lo.v;
        }
    }
    const float blin = b_lin[0];
    float c1[4] = {0.f,0.f,0.f,0.f}, c2[4] = {0.f,0.f,0.f,0.f};

    // x staging: lane (w<3, d=4w+quad<11, ncol=batch) owns x[.][base+ncol][d]
    const int  xd   = w * 4 + quad;
    const bool xact = (w < 3) && (xd < D_INP);
    if (xact) {
        float x0 = input[(size_t)(base + ncol) * D_INP + xd];
        unsigned short xh = f2bf(x0);
        int si = bidx(xd, ncol);
        sB1h[si] = xh; sB1l[si] = f2bf(x0 - bf2f(xh));
    }
    __syncthreads();

    for (int t = 0; t <= T_STEPS; ++t) {
        // ---- frag reads: B1 (x(t),h1(t-1)) and B2 tail (h2(t-1)) ----
        bf16x8 b1hf[2], b1lf[2], b2hf[4], b2lf[4];
        #pragma unroll
        for (int ks = 0; ks < 2; ++ks) {
            const int o = ks * 544 + quad * 136 + ncol * 8;
            b1hf[ks] = *(const bf16x8*)(sB1h + o);
            b1lf[ks] = *(const bf16x8*)(sB1l + o);
        }
        #pragma unroll
        for (int ks = 2; ks < 4; ++ks) {
            const int o = ks * 544 + quad * 136 + ncol * 8;
            b2hf[ks] = *(const bf16x8*)(sB2h + o);
            b2lf[ks] = *(const bf16x8*)(sB2l + o);
        }
        // prefetch x(t+1)
        float xg = 0.0f;
        if (xact) {
            int tn = (t + 1 < T_STEPS) ? t + 1 : T_STEPS - 1;
            xg = input[((size_t)tn * M_BATCH + base + ncol) * D_INP + xd];
        }

        // ---- layer 1: MFMA + in-register cell update ----
        float h1r[4];
        {
            f32x4 acc[4];
            #pragma unroll
            for (int s = 0; s < 4; ++s) {
                f32x4 a = {0.f,0.f,0.f,0.f};
                #pragma unroll
                for (int ks = 0; ks < 2; ++ks) {
                    a = MFMA(a1h[s][ks], b1hf[ks], a);
                    a = MFMA(a1h[s][ks], b1lf[ks], a);
                    a = MFMA(a1l[s][ks], b1hf[ks], a);
                }
                acc[s] = a;
            }
            #pragma unroll
            for (int r = 0; r < 4; ++r) {
                float iv = sigm(acc[0][r]);
                float fv = sigm(acc[1][r]);
                float gv = tanh_fast(acc[2][r]);
                float ov = sigm(acc[3][r]);
                c1[r] = fv * c1[r] + iv * gv;
                h1r[r] = ov * tanh_fast(c1[r]);
            }
            if (w == 3 && quad == 3) h1r[3] = 1.0f;   // maintain B2 bias column k=63
        }
        __syncthreads();   // all B1 / B2-tail reads done

        // ---- write h1(t) -> B1(k=12+u) & B2(k=u); x(t+1) -> B1(k<11) ----
        {
            unsigned short p0 = f2bf(h1r[0]), p1 = f2bf(h1r[1]), p2 = f2bf(h1r[2]), p3 = f2bf(h1r[3]);
            uint2 vh, vl;
            vh.x = p0 | ((unsigned)p1 << 16);
            vh.y = p2 | ((unsigned)p3 << 16);
            vl.x = (unsigned)f2bf(h1r[0] - bf2f(p0)) | ((unsigned)f2bf(h1r[1] - bf2f(p1)) << 16);
            vl.y = (unsigned)f2bf(h1r[2] - bf2f(p2)) | ((unsigned)f2bf(h1r[3] - bf2f(p3)) << 16);
            const int kb2 = w * 16 + quad * 4;        // u base (multiple of 4)
            const int s2  = bidx(kb2, ncol);
            *(uint2*)(sB2h + s2) = vh; *(uint2*)(sB2l + s2) = vl;
            const int kb1 = 12 + kb2;
            if (kb1 <= 60) {                          // stay inside K=64 (skips w3 quads 1-3)
                const int s1 = bidx(kb1, ncol);
                *(uint2*)(sB1h + s1) = vh; *(uint2*)(sB1l + s1) = vl;
            }
            if (xact) {
                unsigned short xh = f2bf(xg);
                int si = bidx(xd, ncol);
                sB1h[si] = xh; sB1l[si] = f2bf(xg - bf2f(xh));
            }
        }
        __syncthreads();   // h1(t) visible

        // ---- layer 2: MFMA + update + fused projection ----
        {
            #pragma unroll
            for (int ks = 0; ks < 2; ++ks) {
                const int o = ks * 544 + quad * 136 + ncol * 8;
                b2hf[ks] = *(const bf16x8*)(sB2h + o);
                b2lf[ks] = *(const bf16x8*)(sB2l + o);
            }
            f32x4 acc[4];
            #pragma unroll
            for (int s = 0; s < 4; ++s) {
                f32x4 a = {0.f,0.f,0.f,0.f};
                #pragma unroll
                for (int ks = 0; ks < 4; ++ks) {
                    a = MFMA(a2h[s][ks], b2hf[ks], a);
                    a = MFMA(a2h[s][ks], b2lf[ks], a);
                    a = MFMA(a2l[s][ks], b2hf[ks], a);
                }
                acc[s] = a;
            }
            const bool hij = (w == 3 && quad == 3);   // lane group holding D row 255
            float vout = acc[3][3] + blin;            // = W_lin · h2(t-1) + b_lin
            float h2r[4];
            #pragma unroll
            for (int r = 0; r < 4; ++r) {
                float iv = sigm(acc[0][r]);
                float fv = sigm(acc[1][r]);
                float gv = tanh_fast(acc[2][r]);
                float ov = sigm(acc[3][r]);
                if (r == 3 && hij) ov = 0.0f;         // keep h2[63] == 0
                c2[r] = fv * c2[r] + iv * gv;
                h2r[r] = ov * tanh_fast(c2[r]);
            }
            if (hij && t > 0)
                out[(size_t)(base + ncol) * T_STEPS + (t - 1)] = vout;

            unsigned short p0 = f2bf(h2r[0]), p1 = f2bf(h2r[1]), p2 = f2bf(h2r[2]), p3 = f2bf(h2r[3]);
            uint2 vh, vl;
            vh.x = p0 | ((unsigned)p1 << 16);
            vh.y = p2 | ((unsigned)p3 << 16);
            vl.x = (unsigned)f2bf(h2r[0] - bf2f(p0)) | ((unsigned)f2bf(h2r[1] - bf2f(p1)) << 16);
            vl.y = (unsigned)f2bf(h2r[2] - bf2f(p2)) | ((unsigned)f2bf(h2r[3] - bf2f(p3)) << 16);
            const int kb = 64 + w * 16 + quad * 4;
            const int s2 = bidx(kb, ncol);
            *(uint2*)(sB2h + s2) = vh; *(uint2*)(sB2l + s2) = vl;
        }
        __syncthreads();   // h2(t) visible for next iteration's tail reads
    }
}

extern "C" void kernel_launch(void* const* d_in, const int* in_sizes, int n_in,
                              void* d_out, int out_size, void* d_ws, size_t ws_size,
                              hipStream_t stream) {
    const float* input = (const float*)d_in[0];
    const float* W_ih1 = (const float*)d_in[1];
    const float* W_hh1 = (const float*)d_in[2];
    const float* b_ih1 = (const float*)d_in[3];
    const float* b_hh1 = (const float*)d_in[4];
    const float* W_ih2 = (const float*)d_in[5];
    const float* W_hh2 = (const float*)d_in[6];
    const float* b_ih2 = (const float*)d_in[7];
    const float* b_hh2 = (const float*)d_in[8];
    const float* W_lin = (const float*)d_in[9];
    const float* b_lin = (const float*)d_in[10];
    float* out = (float*)d_out;

    lstm2_mfma4<<<M_BATCH / BT, THREADS, 0, stream>>>(
        input, W_ih1, W_hh1, b_ih1, b_hh1,
        W_ih2, W_hh2, b_ih2, b_hh2, W_lin, b_lin, out);
}

// Round 5
// 7674.336 us; speedup vs baseline: 2.5881x; 2.5439x over previous
//
#include <hip/hip_runtime.h>

#define T_STEPS 4096
#define M_BATCH 512
#define D_INP   11
#define N_HID   51
#define G4      204

__device__ __forceinline__ float tanh_fast(float v) {
    return 2.0f * __builtin_amdgcn_rcpf(1.0f + __expf(-2.0f * v)) - 1.0f;
}

// Phase-pipelined 2-layer LSTM: one block per batch column, 256 threads.
// Phase A: gate threads j<204 compute L1 gate j for step t AND L2 gate j for
//          step t-1 (L2(t-1) depends only on h1(t-1), h2(t-2) -> independent
//          of L1(t)), plus activations.  Phase B: 51 lanes update c1/h1(t),
//          wave 1 updates c2/h2(t-1) + fused W_lin projection, wave 2 flushes
//          chunked outputs.  2 barriers/step.  x staged in LDS 64 steps at a
//          time (issued 32+ steps ahead of the barrier that drains them).
__global__ __launch_bounds__(256, 2)
void lstm2_pipe(const float* __restrict__ input,
                const float* __restrict__ W_ih1, const float* __restrict__ W_hh1,
                const float* __restrict__ b_ih1, const float* __restrict__ b_hh1,
                const float* __restrict__ W_ih2, const float* __restrict__ W_hh2,
                const float* __restrict__ b_ih2, const float* __restrict__ b_hh2,
                const float* __restrict__ W_lin, const float* __restrict__ b_lin,
                float* __restrict__ out)
{
    const int  tid = threadIdx.x;
    const int  col = blockIdx.x;
    const bool isg = tid < G4;
    const int  j   = isg ? tid : 0;

    __shared__ float hbuf[4][52];      // [0..1] = h1 double-buf, [2..3] = h2 double-buf
    __shared__ float act1[208];
    __shared__ float act2[208];
    __shared__ float xs[2][64 * 12];   // x chunk double-buf, stride 12 per step
    __shared__ float outbuf[128];

    // ---- per-thread persistent weights (fp32) ----
    float wi1[D_INP], wh1[N_HID], wi2[N_HID], wh2[N_HID];
    float bias1 = 0.f, bias2 = 0.f;
    if (isg) {
        #pragma unroll
        for (int k = 0; k < D_INP; ++k) wi1[k] = W_ih1[j * D_INP + k];
        #pragma unroll
        for (int k = 0; k < N_HID; ++k) wh1[k] = W_hh1[j * N_HID + k];
        #pragma unroll
        for (int k = 0; k < N_HID; ++k) wi2[k] = W_ih2[j * N_HID + k];
        #pragma unroll
        for (int k = 0; k < N_HID; ++k) wh2[k] = W_hh2[j * N_HID + k];
        bias1 = b_ih1[j] + b_hh1[j];
        bias2 = b_ih2[j] + b_hh2[j];
    }
    // act = Aa*sigmoid(Sa*v)+Ba  (tanh for the g-gate rows), branch-free
    const bool  gg = (j >= 2 * N_HID) && (j < 3 * N_HID);
    const float Sa = gg ? 2.f : 1.f, Aa = gg ? 2.f : 1.f, Ba = gg ? -1.f : 0.f;

    const int   u2   = tid - 64;                          // wave-1 unit index
    const float wlin = (tid >= 64 && tid < 64 + N_HID) ? W_lin[u2] : 0.f;
    const float blin = b_lin[0];
    float c1 = 0.f, c2 = 0.f;

    if (tid < 4 * 52) (&hbuf[0][0])[tid] = 0.f;

    // x chunk element mapping: e in [0,704): s = e/11 (step-in-chunk), d = e%11
    auto xload = [&](int c, int e) -> float {
        int s = e / 11, d = e - s * 11;
        int tc = c * 64 + s; if (tc > T_STEPS - 1) tc = T_STEPS - 1;
        return input[((size_t)tc * M_BATCH + col) * D_INP + d];
    };
    auto xput = [&](int buf, int e, float v) {
        int s = e / 11, d = e - s * 11;
        xs[buf][s * 12 + d] = v;
    };

    // preload chunk 0
    {
        float v0 = xload(0, tid);
        float v1 = xload(0, tid + 256);
        float v2 = (tid < 192) ? xload(0, tid + 512) : 0.f;
        xput(0, tid, v0);
        xput(0, tid + 256, v1);
        if (tid < 192) xput(0, tid + 512, v2);
    }
    __syncthreads();

    float xr0 = 0.f, xr1 = 0.f, xr2 = 0.f;   // in-flight next-chunk values

    for (int t = 0; t <= T_STEPS; ++t) {
        // ================= phase A =================
        if ((t & 63) == 0) {                 // issue next chunk's loads (32+ steps early)
            const int c = (t >> 6) + 1;
            xr0 = xload(c, tid);
            xr1 = xload(c, tid + 256);
            if (tid < 192) xr2 = xload(c, tid + 512);
        }
        if (isg) {
            const float* xp  = &xs[(t >> 6) & 1][(t & 63) * 12];
            const float* h1p = hbuf[(t + 1) & 1];      // h1(t-1)
            const float* h2p = hbuf[2 + (t & 1)];      // h2(t-2)
            float a[4] = {bias1, 0.f, 0.f, 0.f};
            #pragma unroll
            for (int k = 0; k < D_INP; ++k) a[k & 3] += xp[k] * wi1[k];
            #pragma unroll
            for (int k = 0; k < N_HID; ++k) a[k & 3] += h1p[k] * wh1[k];
            float g1 = (a[0] + a[1]) + (a[2] + a[3]);
            act1[j] = Aa * __builtin_amdgcn_rcpf(1.f + __expf(-Sa * g1)) + Ba;

            float b[4] = {bias2, 0.f, 0.f, 0.f};
            #pragma unroll
            for (int k = 0; k < N_HID; ++k) b[k & 3] += h1p[k] * wi2[k];
            #pragma unroll
            for (int k = 0; k < N_HID; ++k) b[k & 3] += h2p[k] * wh2[k];
            float g2 = (b[0] + b[1]) + (b[2] + b[3]);
            act2[j] = Aa * __builtin_amdgcn_rcpf(1.f + __expf(-Sa * g2)) + Ba;
        }
        __syncthreads();                                   // B1

        // ================= phase B =================
        if (tid < N_HID) {                                 // c1/h1 update for step t
            float iv = act1[tid],            fv = act1[N_HID + tid];
            float gv = act1[2 * N_HID + tid], ov = act1[3 * N_HID + tid];
            c1 = fv * c1 + iv * gv;
            hbuf[t & 1][tid] = ov * tanh_fast(c1);         // h1(t)
        }
        if (tid >= 64 && tid < 128) {                      // c2/h2 update for step t-1
            float part = 0.f;
            if (u2 < N_HID && t >= 1) {
                float iv = act2[u2],            fv = act2[N_HID + u2];
                float gv = act2[2 * N_HID + u2], ov = act2[3 * N_HID + u2];
                c2 = fv * c2 + iv * gv;
                float h2v = ov * tanh_fast(c2);
                hbuf[2 + ((t - 1) & 1)][u2] = h2v;         // h2(t-1)
                part = wlin * h2v;
            }
            #pragma unroll
            for (int off = 32; off > 0; off >>= 1)
                part += __shfl_down(part, off, 64);
            if (u2 == 0 && t >= 1) outbuf[(t - 1) & 127] = part + blin;
        }
        if ((t & 63) == 32) {                              // stash next x chunk
            const int buf = ((t >> 6) + 1) & 1;
            xput(buf, tid, xr0);
            xput(buf, tid + 256, xr1);
            if (tid < 192) xput(buf, tid + 512, xr2);
        }
        if ((t & 63) == 1 && t >= 65 && tid >= 128 && tid < 192) {  // flush outputs
            const int tb = (t - 65) + (tid - 128);
            out[(size_t)col * T_STEPS + tb] = outbuf[tb & 127];
        }
        __syncthreads();                                   // B2
    }

    // final 64 outputs (t-1 = 4032..4095, slots 64..127)
    if (tid >= 128 && tid < 192) {
        const int idx = 4032 + (tid - 128);
        out[(size_t)col * T_STEPS + idx] = outbuf[idx & 127];
    }
}

extern "C" void kernel_launch(void* const* d_in, const int* in_sizes, int n_in,
                              void* d_out, int out_size, void* d_ws, size_t ws_size,
                              hipStream_t stream) {
    const float* input = (const float*)d_in[0];
    const float* W_ih1 = (const float*)d_in[1];
    const float* W_hh1 = (const float*)d_in[2];
    const float* b_ih1 = (const float*)d_in[3];
    const float* b_hh1 = (const float*)d_in[4];
    const float* W_ih2 = (const float*)d_in[5];
    const float* W_hh2 = (const float*)d_in[6];
    const float* b_ih2 = (const float*)d_in[7];
    const float* b_hh2 = (const float*)d_in[8];
    const float* W_lin = (const float*)d_in[9];
    const float* b_lin = (const float*)d_in[10];
    float* out = (float*)d_out;

    lstm2_pipe<<<M_BATCH, 256, 0, stream>>>(
        input, W_ih1, W_hh1, b_ih1, b_hh1,
        W_ih2, W_hh2, b_ih2, b_hh2, W_lin, b_lin, out);
}

// Round 6
// 4461.349 us; speedup vs baseline: 4.4520x; 1.7202x over previous
//
#include <hip/hip_runtime.h>

#define T_STEPS 4096
#define M_BATCH 512
#define D_INP   11
#define N_HID   51
#define G4      204

typedef float v4f __attribute__((ext_vector_type(4)));

__device__ __forceinline__ float tanh_fast(float v) {
    return 2.0f * __builtin_amdgcn_rcpf(1.0f + __expf(-2.0f * v)) - 1.0f;
}

// 2-phase pipelined 2-layer LSTM, one block per batch column.
// Phase A: gate thread j computes L1 gate j of step t AND L2 gate j of step
// t-1 (needs only h1(t-1), h2(t-2)) with v4f LDS broadcast reads; h1(t-1) is
// read ONCE and feeds both dot products.  Phase B: wave0 updates c1/h1(t),
// wave1 updates c2/h2(t-1) + fused projection, wave2 flushes outputs.
// 2 barriers/step.  x staged per 64-step chunk, issued 32 steps early.
__attribute__((amdgpu_waves_per_eu(2, 2)))
__global__ __launch_bounds__(256)
void lstm2_pipe2(const float* __restrict__ input,
                 const float* __restrict__ W_ih1, const float* __restrict__ W_hh1,
                 const float* __restrict__ b_ih1, const float* __restrict__ b_hh1,
                 const float* __restrict__ W_ih2, const float* __restrict__ W_hh2,
                 const float* __restrict__ b_ih2, const float* __restrict__ b_hh2,
                 const float* __restrict__ W_lin, const float* __restrict__ b_lin,
                 float* __restrict__ out)
{
    const int  tid = threadIdx.x;
    const int  col = blockIdx.x;
    const bool isg = tid < G4;
    const int  j   = isg ? tid : 0;

    __shared__ __align__(16) float hbuf[4][52];   // h1 dbuf (0,1), h2 dbuf (2,3); [51]=0 pad
    __shared__ __align__(16) float xs[2][64 * 12]; // x chunks, stride 12, [11]=0 pad
    __shared__ float act1[208];
    __shared__ float act2[208];
    __shared__ float outbuf[128];

    // ---- per-thread persistent weights, packed v4f (zero-padded) ----
    v4f wi1v[3], wh1v[13], wi2v[13], wh2v[13];
    #pragma unroll
    for (int i = 0; i < 3; ++i)
        #pragma unroll
        for (int e = 0; e < 4; ++e) {
            int k = i * 4 + e;
            wi1v[i][e] = (k < D_INP) ? W_ih1[j * D_INP + k] : 0.f;
        }
    #pragma unroll
    for (int i = 0; i < 13; ++i)
        #pragma unroll
        for (int e = 0; e < 4; ++e) {
            int k = i * 4 + e;
            float w1 = (k < N_HID) ? W_hh1[j * N_HID + k] : 0.f;
            float w2 = (k < N_HID) ? W_ih2[j * N_HID + k] : 0.f;
            float w3 = (k < N_HID) ? W_hh2[j * N_HID + k] : 0.f;
            wh1v[i][e] = w1; wi2v[i][e] = w2; wh2v[i][e] = w3;
        }
    const float bias1 = isg ? (b_ih1[j] + b_hh1[j]) : 0.f;
    const float bias2 = isg ? (b_ih2[j] + b_hh2[j]) : 0.f;
    const bool  gg = (j >= 2 * N_HID) && (j < 3 * N_HID);
    const float Sa = gg ? 2.f : 1.f, Aa = gg ? 2.f : 1.f, Ba = gg ? -1.f : 0.f;

    const int   u2   = tid - 64;
    const float wlin = (tid >= 64 && tid < 64 + N_HID) ? W_lin[u2] : 0.f;
    const float blin = b_lin[0];
    float c1 = 0.f, c2 = 0.f;

    if (tid < 208) (&hbuf[0][0])[tid] = 0.f;
    { float* xf = &xs[0][0];
      for (int i = tid; i < 2 * 64 * 12; i += 256) xf[i] = 0.f; }

    auto xload = [&](int c, int e) -> float {      // e in [0,704)
        int s = e / 11, d = e - s * 11;
        int tc = c * 64 + s; if (tc > T_STEPS - 1) tc = T_STEPS - 1;
        return input[((size_t)tc * M_BATCH + col) * D_INP + d];
    };
    auto xput = [&](int buf, int e, float v) {
        int s = e / 11, d = e - s * 11;
        xs[buf][s * 12 + d] = v;
    };
    __syncthreads();   // xs zero-init visible before chunk-0 fill

    {
        float v0 = xload(0, tid);
        float v1 = xload(0, tid + 256);
        float v2 = (tid < 192) ? xload(0, tid + 512) : 0.f;
        xput(0, tid, v0);
        xput(0, tid + 256, v1);
        if (tid < 192) xput(0, tid + 512, v2);
    }
    __syncthreads();

    float xr0 = 0.f, xr1 = 0.f, xr2 = 0.f;

    for (int t = 0; t <= T_STEPS; ++t) {
        // ================= phase A =================
        if ((t & 63) == 0) {                       // issue next chunk 32+ steps early
            const int c = (t >> 6) + 1;
            xr0 = xload(c, tid);
            xr1 = xload(c, tid + 256);
            if (tid < 192) xr2 = xload(c, tid + 512);
        }
        if (isg) {
            const v4f* xp  = (const v4f*)&xs[(t >> 6) & 1][(t & 63) * 12];
            const v4f* h1p = (const v4f*)hbuf[(t + 1) & 1];   // h1(t-1)
            const v4f* h2p = (const v4f*)hbuf[2 + (t & 1)];   // h2(t-2)

            v4f a0 = xp[0] * wi1v[0];
            v4f a1 = xp[1] * wi1v[1];
            a0 += xp[2] * wi1v[2];
            v4f b0 = {0.f, 0.f, 0.f, 0.f}, b1 = {0.f, 0.f, 0.f, 0.f};
            #pragma unroll
            for (int i = 0; i < 13; ++i) {         // h1 read once, used twice
                v4f h = h1p[i];
                if (i & 1) { a1 += h * wh1v[i]; b1 += h * wi2v[i]; }
                else       { a0 += h * wh1v[i]; b0 += h * wi2v[i]; }
            }
            #pragma unroll
            for (int i = 0; i < 13; ++i) {
                v4f h = h2p[i];
                if (i & 1) b1 += h * wh2v[i];
                else       b0 += h * wh2v[i];
            }
            v4f as = a0 + a1;
            float g1 = (as.x + as.y) + (as.z + as.w) + bias1;
            act1[j] = Aa * __builtin_amdgcn_rcpf(1.f + __expf(-Sa * g1)) + Ba;
            v4f bs = b0 + b1;
            float g2 = (bs.x + bs.y) + (bs.z + bs.w) + bias2;
            act2[j] = Aa * __builtin_amdgcn_rcpf(1.f + __expf(-Sa * g2)) + Ba;
        }
        __syncthreads();                           // B1

        // ================= phase B =================
        if (tid < N_HID) {                         // c1/h1 update, step t
            float iv = act1[tid],             fv = act1[N_HID + tid];
            float gv = act1[2 * N_HID + tid], ov = act1[3 * N_HID + tid];
            c1 = fv * c1 + iv * gv;
            hbuf[t & 1][tid] = ov * tanh_fast(c1);
        }
        if (tid >= 64 && tid < 128) {              // c2/h2 update, step t-1 + proj
            float part = 0.f;
            if (u2 < N_HID && t >= 1) {
                float iv = act2[u2],             fv = act2[N_HID + u2];
                float gv = act2[2 * N_HID + u2], ov = act2[3 * N_HID + u2];
                c2 = fv * c2 + iv * gv;
                float h2v = ov * tanh_fast(c2);
                hbuf[2 + ((t - 1) & 1)][u2] = h2v;
                part = wlin * h2v;
            }
            #pragma unroll
            for (int off = 32; off > 0; off >>= 1)
                part += __shfl_down(part, off, 64);
            if (u2 == 0 && t >= 1) outbuf[(t - 1) & 127] = part + blin;
        }
        if ((t & 63) == 32) {                      // stash next x chunk
            const int buf = ((t >> 6) + 1) & 1;
            xput(buf, tid, xr0);
            xput(buf, tid + 256, xr1);
            if (tid < 192) xput(buf, tid + 512, xr2);
        }
        if ((t & 63) == 1 && t >= 65 && tid >= 128 && tid < 192) {
            const int tb = (t - 65) + (tid - 128); // coalesced 64-wide out flush
            out[(size_t)col * T_STEPS + tb] = outbuf[tb & 127];
        }
        __syncthreads();                           // B2
    }

    if (tid >= 128 && tid < 192) {                 // final 64 outputs
        const int idx = 4032 + (tid - 128);
        out[(size_t)col * T_STEPS + idx] = outbuf[idx & 127];
    }
}

extern "C" void kernel_launch(void* const* d_in, const int* in_sizes, int n_in,
                              void* d_out, int out_size, void* d_ws, size_t ws_size,
                              hipStream_t stream) {
    const float* input = (const float*)d_in[0];
    const float* W_ih1 = (const float*)d_in[1];
    const float* W_hh1 = (const float*)d_in[2];
    const float* b_ih1 = (const float*)d_in[3];
    const float* b_hh1 = (const float*)d_in[4];
    const float* W_ih2 = (const float*)d_in[5];
    const float* W_hh2 = (const float*)d_in[6];
    const float* b_ih2 = (const float*)d_in[7];
    const float* b_hh2 = (const float*)d_in[8];
    const float* W_lin = (const float*)d_in[9];
    const float* b_lin = (const float*)d_in[10];
    float* out = (float*)d_out;

    lstm2_pipe2<<<M_BATCH, 256, 0, stream>>>(
        input, W_ih1, W_hh1, b_ih1, b_hh1,
        W_ih2, W_hh2, b_ih2, b_hh2, W_lin, b_lin, out);
}